// Round 2
// baseline (366.963 us; speedup 1.0000x reference)
//
#include <hip/hip_runtime.h>

#define GLOBAL_AS __attribute__((address_space(1)))
#define LDS_AS __attribute__((address_space(3)))

typedef unsigned short u16;
typedef unsigned int u32;
typedef __bf16 bf16x8 __attribute__((ext_vector_type(8)));
typedef float f32x4 __attribute__((ext_vector_type(4)));

static constexpr int BB = 8;        // batch
static constexpr int TT = 2048;     // time
static constexpr int DD = 1024;     // feature dim
static constexpr int MM = BB * TT;  // 16384 rows
static constexpr int KK = DD;       // 1024
static constexpr int NC = 64;       // scan chunks per sequence
static constexpr int CL = TT / NC;  // 32 timesteps per chunk
static constexpr int NCH = BB * NC; // 512 total chunks

__device__ __forceinline__ u16 f2bf(float f) {
  union { float f; u32 u; } c; c.f = f;
  u32 u = c.u;
  u32 r = (u + 0x7fffu + ((u >> 16) & 1u)) >> 16;  // RNE
  return (u16)r;
}

// ---------------- pass 0a: x fp32 -> bf16 ----------------
__global__ void cvt_x_kernel(const float* __restrict__ x, u16* __restrict__ xb) {
  int i = (blockIdx.x * blockDim.x + threadIdx.x) * 8;
  const float4* p = reinterpret_cast<const float4*>(x + i);
  float4 v0 = p[0], v1 = p[1];
  u16 r0 = f2bf(v0.x), r1 = f2bf(v0.y), r2 = f2bf(v0.z), r3 = f2bf(v0.w);
  u16 r4 = f2bf(v1.x), r5 = f2bf(v1.y), r6 = f2bf(v1.z), r7 = f2bf(v1.w);
  uint4 o;
  o.x = (u32)r0 | ((u32)r1 << 16);
  o.y = (u32)r2 | ((u32)r3 << 16);
  o.z = (u32)r4 | ((u32)r5 << 16);
  o.w = (u32)r6 | ((u32)r7 << 16);
  *reinterpret_cast<uint4*>(xb + i) = o;
}

// ---------------- pass 0b: W fp32 [k][n] -> bf16 W^T [n][k] ----------------
__global__ void cvt_w_kernel(const float* __restrict__ Wz, const float* __restrict__ Wh,
                             u16* __restrict__ WT) {
  __shared__ float tile[32][33];
  int w = blockIdx.z;
  const float* W = w ? Wh : Wz;
  u16* O = WT + (size_t)w * DD * KK;
  int k0 = blockIdx.y * 32;
  int n0 = blockIdx.x * 32;
  int tx = threadIdx.x, ty = threadIdx.y;
  for (int i = 0; i < 32; i += 8)
    tile[ty + i][tx] = W[(size_t)(k0 + ty + i) * DD + n0 + tx];
  __syncthreads();
  for (int i = 0; i < 32; i += 8)
    O[(size_t)(n0 + ty + i) * KK + k0 + tx] = f2bf(tile[tx][ty + i]);
}

// ---------------- pass 1: dual GEMM + gate epilogue + fused chunk-reduce ----------------
// zpre = x*Wz + bz ; hpre = x*Wh + bh ; a = 1-sigmoid(zpre) ; b = sigmoid(zpre)*hpre
// Each wave's 32 rows == exactly one scan chunk (CL=32): compose (A,B) in-register.
__global__ __launch_bounds__(256) void gemm_dual_kernel(
    const u16* __restrict__ xb,   // [MM][KK] bf16
    const u16* __restrict__ WT,   // [2][DD][KK] bf16 (n-major)
    const float* __restrict__ bz, const float* __restrict__ bh,
    float* __restrict__ a_out, float* __restrict__ bb_out,
    float* __restrict__ Asum, float* __restrict__ Bsum) {
  __shared__ __align__(16) u16 As[128 * 32];
  __shared__ __align__(16) u16 Bzs[64 * 32];
  __shared__ __align__(16) u16 Bhs[64 * 32];

  int bid = blockIdx.x;
  int nt = bid & 15;    // 16 n-tiles (consecutive blocks share the A m-tile in L2)
  int mt = bid >> 4;    // 128 m-tiles
  int m0 = mt * 128, n0 = nt * 64;

  int tid = threadIdx.x;
  int lane = tid & 63;
  int wave = tid >> 6;

  // staging: thread's flat bf16 dest elem = tid*8 (+2048 for A issue 1)
  int drow = tid >> 2;          // 0..63
  int dk = (tid & 3) * 8;
  const u16* Ag0 = xb + (size_t)(m0 + drow) * KK + dk;
  const u16* Ag1 = Ag0 + (size_t)64 * KK;
  const u16* Bzg = WT + (size_t)(n0 + drow) * KK + dk;
  const u16* Bhg = Bzg + (size_t)DD * KK;

  u16* As0W = As + wave * 512;          // wave-uniform base, lane lands at +lane*16B
  u16* As1W = As + 2048 + wave * 512;
  u16* BzsW = Bzs + wave * 512;
  u16* BhsW = Bhs + wave * 512;

  f32x4 accz[2][4];   // [i: 16-row tile][j: 16-col tile]
  f32x4 acch[2][4];
  for (int i = 0; i < 2; i++)
    for (int j = 0; j < 4; j++) {
      accz[i][j] = (f32x4){0.f, 0.f, 0.f, 0.f};
      acch[i][j] = (f32x4){0.f, 0.f, 0.f, 0.f};
    }

  int RM = wave * 32;           // wave's 32 rows = one chunk
  int fr = lane & 15;
  int fk = (lane >> 4) * 8;

  for (int k0i = 0; k0i < KK; k0i += 32) {
    __builtin_amdgcn_global_load_lds((const GLOBAL_AS void*)(Ag0 + k0i), (LDS_AS void*)As0W, 16, 0, 0);
    __builtin_amdgcn_global_load_lds((const GLOBAL_AS void*)(Ag1 + k0i), (LDS_AS void*)As1W, 16, 0, 0);
    __builtin_amdgcn_global_load_lds((const GLOBAL_AS void*)(Bzg + k0i), (LDS_AS void*)BzsW, 16, 0, 0);
    __builtin_amdgcn_global_load_lds((const GLOBAL_AS void*)(Bhg + k0i), (LDS_AS void*)BhsW, 16, 0, 0);
    __syncthreads();  // drains vmcnt -> staging visible

    bf16x8 af[2], bzf[4], bhf[4];
    for (int i = 0; i < 2; i++)
      af[i] = *reinterpret_cast<const bf16x8*>(As + (RM + i * 16 + fr) * 32 + fk);
    for (int j = 0; j < 4; j++) {
      bzf[j] = *reinterpret_cast<const bf16x8*>(Bzs + (j * 16 + fr) * 32 + fk);
      bhf[j] = *reinterpret_cast<const bf16x8*>(Bhs + (j * 16 + fr) * 32 + fk);
    }
    for (int i = 0; i < 2; i++)
      for (int j = 0; j < 4; j++) {
        accz[i][j] = __builtin_amdgcn_mfma_f32_16x16x32_bf16(af[i], bzf[j], accz[i][j], 0, 0, 0);
        acch[i][j] = __builtin_amdgcn_mfma_f32_16x16x32_bf16(af[i], bhf[j], acch[i][j], 0, 0, 0);
      }
    __syncthreads();  // tiles consumed before restage
  }

  // epilogue: D[row = RM + i*16 + quad*4 + r][col = n0 + j*16 + fr]
  // + ordered chunk composition over the wave's 32 rows (t ascending = row ascending)
  int quad = lane >> 4;
  int cg = mt * 4 + wave;       // global chunk id = (m0+RM)/32
  for (int j = 0; j < 4; j++) {
    int n = n0 + j * 16 + fr;
    float bzv = bz[n], bhv = bh[n];
    float Ai[2], Bi[2];
    for (int i = 0; i < 2; i++) {
      float Aloc = 1.f, Bloc = 0.f;
      int mbase = m0 + RM + i * 16 + quad * 4;
      for (int r = 0; r < 4; r++) {
        float zp = accz[i][j][r] + bzv;
        float hp = acch[i][j][r] + bhv;
        float zs = 1.0f / (1.0f + __expf(-zp));
        float av = 1.0f - zs;
        float bv = zs * hp;
        size_t idx = (size_t)(mbase + r) * DD + n;
        a_out[idx] = av;
        bb_out[idx] = bv;
        Bloc = av * Bloc + bv;   // t-ascending composition
        Aloc = av * Aloc;
      }
      // ordered cross-quad combine (quads hold rows quad*4..quad*4+3 within the 16-row tile)
      {
        float Ao = __shfl_xor(Aloc, 16, 64);
        float Bo = __shfl_xor(Bloc, 16, 64);
        float Bc = (quad & 1) ? (Aloc * Bo + Bloc) : (Ao * Bloc + Bo);
        float Ac = Aloc * Ao;
        float Ao2 = __shfl_xor(Ac, 32, 64);
        float Bo2 = __shfl_xor(Bc, 32, 64);
        Bi[i] = (quad & 2) ? (Ac * Bo2 + Bc) : (Ao2 * Bc + Bo2);
        Ai[i] = Ac * Ao2;
      }
    }
    // combine i0 (rows 0..15) then i1 (rows 16..31)
    float Ack = Ai[1] * Ai[0];
    float Bck = Ai[1] * Bi[0] + Bi[1];
    if (quad == 0) {
      Asum[(size_t)cg * DD + n] = Ack;
      Bsum[(size_t)cg * DD + n] = Bck;
    }
  }
}

// ---------------- pass 2: scan over chunk summaries -> h_in per chunk ----------------
__global__ void chunk_scan_kernel(const float* __restrict__ Asum, const float* __restrict__ Bsum,
                                  float* __restrict__ hin) {
  int tid = blockIdx.x * blockDim.x + threadIdx.x;  // 8192 = [b][d]
  int d = tid & (DD - 1);
  int b = tid >> 10;
  float h = 0.f;
  for (int c = 0; c < NC; c++) {
    int i = (b * NC + c) * DD + d;
    hin[i] = h;
    h = Asum[i] * h + Bsum[i];
  }
}

// ---------------- pass 3: apply recurrence + swish + wave-local LayerNorm ----------------
// One WAVE per chunk: lane owns d = {j*256 + lane*4 .. +3}, j=0..3 (16 channels).
// LN reduction = 6 shuffles, no __syncthreads anywhere.
__global__ __launch_bounds__(256) void apply_ln_kernel(
    const float* __restrict__ a, const float* __restrict__ bb, const float* __restrict__ hin,
    const float* __restrict__ sbeta, const float* __restrict__ gamma,
    const float* __restrict__ lbeta, float* __restrict__ out) {
  int wv = (blockIdx.x << 2) | (threadIdx.x >> 6);  // chunk id 0..511
  int lane = threadIdx.x & 63;
  int b = wv >> 6, c = wv & (NC - 1);
  float sb = sbeta[0];

  float4 g[4], be[4], h[4];
  for (int j = 0; j < 4; j++) {
    g[j]  = *reinterpret_cast<const float4*>(gamma + j * 256 + lane * 4);
    be[j] = *reinterpret_cast<const float4*>(lbeta + j * 256 + lane * 4);
    h[j]  = *reinterpret_cast<const float4*>(hin + (size_t)wv * DD + j * 256 + lane * 4);
  }

  size_t base = ((size_t)b * TT + (size_t)c * CL) * DD + lane * 4;  // + t*DD + j*256

  // depth-3 prefetch ring
  float4 aR[3][4], bR[3][4];
  for (int p = 0; p < 3; p++)
    for (int j = 0; j < 4; j++) {
      aR[p][j] = *reinterpret_cast<const float4*>(a  + base + (size_t)p * DD + j * 256);
      bR[p][j] = *reinterpret_cast<const float4*>(bb + base + (size_t)p * DD + j * 256);
    }

  for (int t = 0; t < CL; t++) {
    int slot = t % 3;
    float sum = 0.f, sq = 0.f;
    float4 y[4];
    for (int j = 0; j < 4; j++) {
      float4 av = aR[slot][j], bv = bR[slot][j];
      h[j].x = av.x * h[j].x + bv.x;
      h[j].y = av.y * h[j].y + bv.y;
      h[j].z = av.z * h[j].z + bv.z;
      h[j].w = av.w * h[j].w + bv.w;
      float sx = sb * h[j].x, sy = sb * h[j].y, sz = sb * h[j].z, sw = sb * h[j].w;
      y[j].x = sx / (1.0f + __expf(-sx));
      y[j].y = sy / (1.0f + __expf(-sy));
      y[j].z = sz / (1.0f + __expf(-sz));
      y[j].w = sw / (1.0f + __expf(-sw));
      sum += y[j].x + y[j].y + y[j].z + y[j].w;
      sq  += y[j].x * y[j].x + y[j].y * y[j].y + y[j].z * y[j].z + y[j].w * y[j].w;
    }
    if (t + 3 < CL) {  // refill ring; overlaps the reduction below
      for (int j = 0; j < 4; j++) {
        aR[slot][j] = *reinterpret_cast<const float4*>(a  + base + (size_t)(t + 3) * DD + j * 256);
        bR[slot][j] = *reinterpret_cast<const float4*>(bb + base + (size_t)(t + 3) * DD + j * 256);
      }
    }
    for (int o = 32; o > 0; o >>= 1) {
      sum += __shfl_xor(sum, o, 64);
      sq  += __shfl_xor(sq, o, 64);
    }
    float mu = sum * (1.0f / DD);
    float var = sq * (1.0f / DD) - mu * mu;
    float inv = rsqrtf(fmaxf(var, 0.f) + 1e-5f);
    for (int j = 0; j < 4; j++) {
      float4 o4;
      o4.x = (y[j].x - mu) * inv * g[j].x + be[j].x;
      o4.y = (y[j].y - mu) * inv * g[j].y + be[j].y;
      o4.z = (y[j].z - mu) * inv * g[j].z + be[j].z;
      o4.w = (y[j].w - mu) * inv * g[j].w + be[j].w;
      *reinterpret_cast<float4*>(out + base + (size_t)t * DD + j * 256) = o4;
    }
  }
}

extern "C" void kernel_launch(void* const* d_in, const int* in_sizes, int n_in,
                              void* d_out, int out_size, void* d_ws, size_t ws_size,
                              hipStream_t stream) {
  const float* x     = (const float*)d_in[0];
  const float* Wz    = (const float*)d_in[1];
  const float* bz    = (const float*)d_in[2];
  const float* Wh    = (const float*)d_in[3];
  const float* bh    = (const float*)d_in[4];
  const float* sbeta = (const float*)d_in[5];
  const float* gamma = (const float*)d_in[6];
  const float* lbeta = (const float*)d_in[7];
  float* out = (float*)d_out;

  char* ws = (char*)d_ws;
  u16* xb     = (u16*)ws;                         // 33,554,432 B
  u16* WT     = (u16*)(ws + 33554432);            //  4,194,304 B
  float* bb   = (float*)(ws + 37748736);          // 67,108,864 B
  float* Asum = (float*)(ws + 104857600);         //  2,097,152 B (512x1024 f32)
  float* Bsum = (float*)(ws + 106954752);         //  2,097,152 B
  float* hin  = (float*)(ws + 109051904);         //  2,097,152 B
  const size_t NEED_BASE = 111149056ull;
  const size_t NEED_FULL = NEED_BASE + 67108864ull;
  float* a_ptr = (ws_size >= NEED_FULL) ? (float*)(ws + NEED_BASE) : out;

  cvt_x_kernel<<<8192, 256, 0, stream>>>(x, xb);
  dim3 tw(32, 8), gw(32, 32, 2);
  cvt_w_kernel<<<gw, tw, 0, stream>>>(Wz, Wh, WT);
  gemm_dual_kernel<<<2048, 256, 0, stream>>>(xb, WT, bz, bh, a_ptr, bb, Asum, Bsum);
  chunk_scan_kernel<<<32, 256, 0, stream>>>(Asum, Bsum, hin);
  apply_ln_kernel<<<128, 256, 0, stream>>>(a_ptr, bb, hin, sbeta, gamma, lbeta, out);
}

// Round 3
// 284.632 us; speedup vs baseline: 1.2893x; 1.2893x over previous
//
#include <hip/hip_runtime.h>

#define GLOBAL_AS __attribute__((address_space(1)))
#define LDS_AS __attribute__((address_space(3)))

typedef unsigned short u16;
typedef unsigned int u32;
typedef __bf16 bf16x8 __attribute__((ext_vector_type(8)));
typedef float f32x4 __attribute__((ext_vector_type(4)));

static constexpr int BB = 8;        // batch
static constexpr int TT = 2048;     // time
static constexpr int DD = 1024;     // feature dim
static constexpr int MM = BB * TT;  // 16384 rows
static constexpr int KK = DD;       // 1024
static constexpr int NC = 64;       // scan chunks per sequence
static constexpr int CL = TT / NC;  // 32 timesteps per chunk
static constexpr int NCH = BB * NC; // 512 total chunks

__device__ __forceinline__ u16 f2bf(float f) {
  union { float f; u32 u; } c; c.f = f;
  u32 u = c.u;
  u32 r = (u + 0x7fffu + ((u >> 16) & 1u)) >> 16;  // RNE
  return (u16)r;
}

// ---------------- pass 0a: x fp32 -> bf16 ----------------
__global__ void cvt_x_kernel(const float* __restrict__ x, u16* __restrict__ xb) {
  int i = (blockIdx.x * blockDim.x + threadIdx.x) * 8;
  const float4* p = reinterpret_cast<const float4*>(x + i);
  float4 v0 = p[0], v1 = p[1];
  u16 r0 = f2bf(v0.x), r1 = f2bf(v0.y), r2 = f2bf(v0.z), r3 = f2bf(v0.w);
  u16 r4 = f2bf(v1.x), r5 = f2bf(v1.y), r6 = f2bf(v1.z), r7 = f2bf(v1.w);
  uint4 o;
  o.x = (u32)r0 | ((u32)r1 << 16);
  o.y = (u32)r2 | ((u32)r3 << 16);
  o.z = (u32)r4 | ((u32)r5 << 16);
  o.w = (u32)r6 | ((u32)r7 << 16);
  *reinterpret_cast<uint4*>(xb + i) = o;
}

// ---------------- pass 0b: W fp32 [k][n] -> bf16 W^T [n][k] ----------------
__global__ void cvt_w_kernel(const float* __restrict__ Wz, const float* __restrict__ Wh,
                             u16* __restrict__ WT) {
  __shared__ float tile[32][33];
  int w = blockIdx.z;
  const float* W = w ? Wh : Wz;
  u16* O = WT + (size_t)w * DD * KK;
  int k0 = blockIdx.y * 32;
  int n0 = blockIdx.x * 32;
  int tx = threadIdx.x, ty = threadIdx.y;
  for (int i = 0; i < 32; i += 8)
    tile[ty + i][tx] = W[(size_t)(k0 + ty + i) * DD + n0 + tx];
  __syncthreads();
  for (int i = 0; i < 32; i += 8)
    O[(size_t)(n0 + ty + i) * KK + k0 + tx] = f2bf(tile[tx][ty + i]);
}

// ---------------- pass 1: dual GEMM + gate epilogue + fused chunk-reduce ----------------
// zpre = x*Wz + bz ; hpre = x*Wh + bh ; a = 1-sigmoid(zpre) ; b = sigmoid(zpre)*hpre
// Each wave's 32 rows == exactly one scan chunk (CL=32): compose (A,B) in-register.
__global__ __launch_bounds__(256) void gemm_dual_kernel(
    const u16* __restrict__ xb,   // [MM][KK] bf16
    const u16* __restrict__ WT,   // [2][DD][KK] bf16 (n-major)
    const float* __restrict__ bz, const float* __restrict__ bh,
    float* __restrict__ a_out, float* __restrict__ bb_out,
    float* __restrict__ Asum, float* __restrict__ Bsum) {
  __shared__ __align__(16) u16 As[128 * 32];
  __shared__ __align__(16) u16 Bzs[64 * 32];
  __shared__ __align__(16) u16 Bhs[64 * 32];

  int bid = blockIdx.x;
  int nt = bid & 15;    // 16 n-tiles (consecutive blocks share the A m-tile in L2)
  int mt = bid >> 4;    // 128 m-tiles
  int m0 = mt * 128, n0 = nt * 64;

  int tid = threadIdx.x;
  int lane = tid & 63;
  int wave = tid >> 6;

  // staging: thread's flat bf16 dest elem = tid*8 (+2048 for A issue 1)
  int drow = tid >> 2;          // 0..63
  int dk = (tid & 3) * 8;
  const u16* Ag0 = xb + (size_t)(m0 + drow) * KK + dk;
  const u16* Ag1 = Ag0 + (size_t)64 * KK;
  const u16* Bzg = WT + (size_t)(n0 + drow) * KK + dk;
  const u16* Bhg = Bzg + (size_t)DD * KK;

  u16* As0W = As + wave * 512;          // wave-uniform base, lane lands at +lane*16B
  u16* As1W = As + 2048 + wave * 512;
  u16* BzsW = Bzs + wave * 512;
  u16* BhsW = Bhs + wave * 512;

  f32x4 accz[2][4];   // [i: 16-row tile][j: 16-col tile]
  f32x4 acch[2][4];
  for (int i = 0; i < 2; i++)
    for (int j = 0; j < 4; j++) {
      accz[i][j] = (f32x4){0.f, 0.f, 0.f, 0.f};
      acch[i][j] = (f32x4){0.f, 0.f, 0.f, 0.f};
    }

  int RM = wave * 32;           // wave's 32 rows = one chunk
  int fr = lane & 15;
  int fk = (lane >> 4) * 8;

  for (int k0i = 0; k0i < KK; k0i += 32) {
    __builtin_amdgcn_global_load_lds((const GLOBAL_AS void*)(Ag0 + k0i), (LDS_AS void*)As0W, 16, 0, 0);
    __builtin_amdgcn_global_load_lds((const GLOBAL_AS void*)(Ag1 + k0i), (LDS_AS void*)As1W, 16, 0, 0);
    __builtin_amdgcn_global_load_lds((const GLOBAL_AS void*)(Bzg + k0i), (LDS_AS void*)BzsW, 16, 0, 0);
    __builtin_amdgcn_global_load_lds((const GLOBAL_AS void*)(Bhg + k0i), (LDS_AS void*)BhsW, 16, 0, 0);
    __syncthreads();  // drains vmcnt -> staging visible

    bf16x8 af[2], bzf[4], bhf[4];
    for (int i = 0; i < 2; i++)
      af[i] = *reinterpret_cast<const bf16x8*>(As + (RM + i * 16 + fr) * 32 + fk);
    for (int j = 0; j < 4; j++) {
      bzf[j] = *reinterpret_cast<const bf16x8*>(Bzs + (j * 16 + fr) * 32 + fk);
      bhf[j] = *reinterpret_cast<const bf16x8*>(Bhs + (j * 16 + fr) * 32 + fk);
    }
    for (int i = 0; i < 2; i++)
      for (int j = 0; j < 4; j++) {
        accz[i][j] = __builtin_amdgcn_mfma_f32_16x16x32_bf16(af[i], bzf[j], accz[i][j], 0, 0, 0);
        acch[i][j] = __builtin_amdgcn_mfma_f32_16x16x32_bf16(af[i], bhf[j], acch[i][j], 0, 0, 0);
      }
    __syncthreads();  // tiles consumed before restage
  }

  // epilogue: D[row = RM + i*16 + quad*4 + r][col = n0 + j*16 + fr]
  // + ordered chunk composition over the wave's 32 rows (t ascending = row ascending)
  int quad = lane >> 4;
  int cg = mt * 4 + wave;       // global chunk id = (m0+RM)/32
  for (int j = 0; j < 4; j++) {
    int n = n0 + j * 16 + fr;
    float bzv = bz[n], bhv = bh[n];
    float Ai[2], Bi[2];
    for (int i = 0; i < 2; i++) {
      float Aloc = 1.f, Bloc = 0.f;
      int mbase = m0 + RM + i * 16 + quad * 4;
      for (int r = 0; r < 4; r++) {
        float zp = accz[i][j][r] + bzv;
        float hp = acch[i][j][r] + bhv;
        float zs = 1.0f / (1.0f + __expf(-zp));
        float av = 1.0f - zs;
        float bv = zs * hp;
        size_t idx = (size_t)(mbase + r) * DD + n;
        a_out[idx] = av;
        bb_out[idx] = bv;
        Bloc = av * Bloc + bv;   // t-ascending composition
        Aloc = av * Aloc;
      }
      // ordered cross-quad combine (quads hold rows quad*4..quad*4+3 within the 16-row tile)
      {
        float Ao = __shfl_xor(Aloc, 16, 64);
        float Bo = __shfl_xor(Bloc, 16, 64);
        float Bc = (quad & 1) ? (Aloc * Bo + Bloc) : (Ao * Bloc + Bo);
        float Ac = Aloc * Ao;
        float Ao2 = __shfl_xor(Ac, 32, 64);
        float Bo2 = __shfl_xor(Bc, 32, 64);
        Bi[i] = (quad & 2) ? (Ac * Bo2 + Bc) : (Ao2 * Bc + Bo2);
        Ai[i] = Ac * Ao2;
      }
    }
    // combine i0 (rows 0..15) then i1 (rows 16..31)
    float Ack = Ai[1] * Ai[0];
    float Bck = Ai[1] * Bi[0] + Bi[1];
    if (quad == 0) {
      Asum[(size_t)cg * DD + n] = Ack;
      Bsum[(size_t)cg * DD + n] = Bck;
    }
  }
}

// ---------------- pass 2: scan over chunk summaries -> h_in per chunk ----------------
__global__ void chunk_scan_kernel(const float* __restrict__ Asum, const float* __restrict__ Bsum,
                                  float* __restrict__ hin) {
  int tid = blockIdx.x * blockDim.x + threadIdx.x;  // 8192 = [b][d]
  int d = tid & (DD - 1);
  int b = tid >> 10;
  float h = 0.f;
#pragma unroll
  for (int c = 0; c < NC; c++) {
    int i = (b * NC + c) * DD + d;
    hin[i] = h;
    h = Asum[i] * h + Bsum[i];
  }
}

// ---------------- pass 3: apply recurrence + swish + fused LayerNorm ----------------
// One BLOCK (4 waves, 256 threads) per chunk; lane owns one float4 of D.
// t-loop FULLY UNROLLED so the prefetch-ring / LDS-slot indices are compile-time
// constants -> everything stays in VGPRs (the round-1/2 version's runtime ring
// index forced the arrays to scratch, which dominated total time).
__global__ __launch_bounds__(256) void apply_ln_kernel(
    const float* __restrict__ a, const float* __restrict__ bb, const float* __restrict__ hin,
    const float* __restrict__ sbeta, const float* __restrict__ gamma,
    const float* __restrict__ lbeta, float* __restrict__ out) {
  __shared__ float ps[2][4];
  __shared__ float pq[2][4];
  int ch = blockIdx.x;                 // chunk id 0..511
  int wv = threadIdx.x >> 6;
  int lane = threadIdx.x & 63;
  int d = wv * 256 + lane * 4;
  int b = ch >> 6, c = ch & (NC - 1);
  float sb = sbeta[0];

  float4 g4 = *reinterpret_cast<const float4*>(gamma + d);
  float4 be4 = *reinterpret_cast<const float4*>(lbeta + d);
  float4 h4 = *reinterpret_cast<const float4*>(hin + (size_t)ch * DD + d);

  size_t base = ((size_t)b * TT + (size_t)c * CL) * DD + d;  // + t*DD

  // depth-3 prefetch ring (statically indexed after full unroll)
  float4 aR[3], bR[3];
#pragma unroll
  for (int p = 0; p < 3; p++) {
    aR[p] = *reinterpret_cast<const float4*>(a + base + (size_t)p * DD);
    bR[p] = *reinterpret_cast<const float4*>(bb + base + (size_t)p * DD);
  }

#pragma unroll
  for (int t = 0; t < CL; t++) {
    const int slot = t % 3;
    const int pslot = t & 1;
    float4 av = aR[slot], bv = bR[slot];
    h4.x = av.x * h4.x + bv.x;
    h4.y = av.y * h4.y + bv.y;
    h4.z = av.z * h4.z + bv.z;
    h4.w = av.w * h4.w + bv.w;
    if (t + 3 < CL) {  // refill ring; overlaps the reduction below
      aR[slot] = *reinterpret_cast<const float4*>(a + base + (size_t)(t + 3) * DD);
      bR[slot] = *reinterpret_cast<const float4*>(bb + base + (size_t)(t + 3) * DD);
    }
    float sx = sb * h4.x, sy = sb * h4.y, sz = sb * h4.z, sw = sb * h4.w;
    float4 y;
    y.x = sx / (1.0f + __expf(-sx));
    y.y = sy / (1.0f + __expf(-sy));
    y.z = sz / (1.0f + __expf(-sz));
    y.w = sw / (1.0f + __expf(-sw));
    float sum = y.x + y.y + y.z + y.w;
    float sq = y.x * y.x + y.y * y.y + y.z * y.z + y.w * y.w;
#pragma unroll
    for (int o = 32; o > 0; o >>= 1) {
      sum += __shfl_xor(sum, o, 64);
      sq += __shfl_xor(sq, o, 64);
    }
    if (lane == 0) { ps[pslot][wv] = sum; pq[pslot][wv] = sq; }
    __syncthreads();
    float tot = ps[pslot][0] + ps[pslot][1] + ps[pslot][2] + ps[pslot][3];
    float totq = pq[pslot][0] + pq[pslot][1] + pq[pslot][2] + pq[pslot][3];
    float mu = tot * (1.0f / DD);
    float var = totq * (1.0f / DD) - mu * mu;
    float inv = rsqrtf(fmaxf(var, 0.f) + 1e-5f);
    float4 o4;
    o4.x = (y.x - mu) * inv * g4.x + be4.x;
    o4.y = (y.y - mu) * inv * g4.y + be4.y;
    o4.z = (y.z - mu) * inv * g4.z + be4.z;
    o4.w = (y.w - mu) * inv * g4.w + be4.w;
    *reinterpret_cast<float4*>(out + base + (size_t)t * DD) = o4;
  }
}

extern "C" void kernel_launch(void* const* d_in, const int* in_sizes, int n_in,
                              void* d_out, int out_size, void* d_ws, size_t ws_size,
                              hipStream_t stream) {
  const float* x     = (const float*)d_in[0];
  const float* Wz    = (const float*)d_in[1];
  const float* bz    = (const float*)d_in[2];
  const float* Wh    = (const float*)d_in[3];
  const float* bh    = (const float*)d_in[4];
  const float* sbeta = (const float*)d_in[5];
  const float* gamma = (const float*)d_in[6];
  const float* lbeta = (const float*)d_in[7];
  float* out = (float*)d_out;

  char* ws = (char*)d_ws;
  u16* xb     = (u16*)ws;                         // 33,554,432 B
  u16* WT     = (u16*)(ws + 33554432);            //  4,194,304 B
  float* bb   = (float*)(ws + 37748736);          // 67,108,864 B
  float* Asum = (float*)(ws + 104857600);         //  2,097,152 B (512x1024 f32)
  float* Bsum = (float*)(ws + 106954752);         //  2,097,152 B
  float* hin  = (float*)(ws + 109051904);         //  2,097,152 B
  const size_t NEED_BASE = 111149056ull;
  const size_t NEED_FULL = NEED_BASE + 67108864ull;
  float* a_ptr = (ws_size >= NEED_FULL) ? (float*)(ws + NEED_BASE) : out;

  cvt_x_kernel<<<8192, 256, 0, stream>>>(x, xb);
  dim3 tw(32, 8), gw(32, 32, 2);
  cvt_w_kernel<<<gw, tw, 0, stream>>>(Wz, Wh, WT);
  gemm_dual_kernel<<<2048, 256, 0, stream>>>(xb, WT, bz, bh, a_ptr, bb, Asum, Bsum);
  chunk_scan_kernel<<<32, 256, 0, stream>>>(Asum, Bsum, hin);
  apply_ln_kernel<<<NCH, 256, 0, stream>>>(a_ptr, bb, hin, sbeta, gamma, lbeta, out);
}